// Round 7
// baseline (204.667 us; speedup 1.0000x reference)
//
#include <hip/hip_runtime.h>

typedef unsigned short u16;
typedef unsigned int u32;
typedef __bf16 bf16x8 __attribute__((ext_vector_type(8)));
typedef float f32x4 __attribute__((ext_vector_type(4)));
typedef u16 u16x8 __attribute__((ext_vector_type(8)));
typedef u16 u16x4 __attribute__((ext_vector_type(4)));

#define DEV static __device__ __forceinline__

template <bool B> struct BC { static constexpr bool value = B; };
template <int I> struct IC { static constexpr int value = I; };

DEV u16 f2bf(float f) {
  unsigned u = __builtin_bit_cast(unsigned, f);
  u += 0x7fffu + ((u >> 16) & 1u);
  return (u16)(u >> 16);
}
DEV u16 f2bf_fast(float f) {
  unsigned u = __builtin_bit_cast(unsigned, f);
  return (u16)((u + 0x8000u) >> 16);
}
DEV float fexp2(float x) {
  float r;
  asm("v_exp_f32 %0, %1" : "=v"(r) : "v"(x));
  return r;
}

DEV void gld16(const void* g, void* l) {
  __builtin_amdgcn_global_load_lds((__attribute__((address_space(1))) void*)(g),
                                   (__attribute__((address_space(3))) void*)(l),
                                   16, 0, 0);
}

// ---------------- cast fp32 -> bf16 ----------------
__global__ __launch_bounds__(256) void k_cast(const float* __restrict__ in,
                                              u16* __restrict__ out, int n4) {
  int i = blockIdx.x * 256 + threadIdx.x;
  if (i >= n4) return;
  float4 v = ((const float4*)in)[i];
  u16x4 r = { f2bf(v.x), f2bf(v.y), f2bf(v.z), f2bf(v.w) };
  ((u16x4*)out)[i] = r;
}

// ---------------- cast + transpose ----------------
__global__ __launch_bounds__(256) void k_transpose_cast(const float* __restrict__ in,
                                                        u16* __restrict__ out,
                                                        int R, int Cc) {
  __shared__ u16 tile[64][65];
  int r0 = blockIdx.x * 64, c0 = blockIdx.y * 64;
  int tid = threadIdx.x;
#pragma unroll
  for (int rr = 0; rr < 4; ++rr) {
    int r = rr * 16 + (tid >> 4);
    int c = (tid & 15) * 4;
    float4 v = *(const float4*)&in[(size_t)(r0 + r) * Cc + c0 + c];
    tile[r][c + 0] = f2bf(v.x); tile[r][c + 1] = f2bf(v.y);
    tile[r][c + 2] = f2bf(v.z); tile[r][c + 3] = f2bf(v.w);
  }
  __syncthreads();
#pragma unroll
  for (int rr = 0; rr < 2; ++rr) {
    int cr = rr * 32 + (tid >> 3);
    int rc = (tid & 7) * 8;
    u16x8 v;
#pragma unroll
    for (int j = 0; j < 8; ++j) v[j] = tile[rc + j][cr];
    *(u16x8*)&out[(size_t)(c0 + cr) * R + r0 + rc] = v;
  }
}

// -------- extract V from qkv, transpose: vt[b][h][d=64][t=1024] bf16 --------
__global__ __launch_bounds__(256) void k_vtrans(const u16* __restrict__ qkv,
                                                u16* __restrict__ vt) {
  __shared__ u16 tile[64][65];
  int bid = blockIdx.x;
  int b = bid >> 8, h = (bid >> 4) & 15, tt = bid & 15;
  int tid = threadIdx.x;
#pragma unroll
  for (int rr = 0; rr < 2; ++rr) {
    int tl = rr * 32 + (tid >> 3);
    int d0 = (tid & 7) * 8;
    u16x8 v = *(const u16x8*)&qkv[(size_t)(b * 1024 + tt * 64 + tl) * 3072 + 2048 + h * 64 + d0];
#pragma unroll
    for (int j = 0; j < 8; ++j) tile[tl][d0 + j] = v[j];
  }
  __syncthreads();
#pragma unroll
  for (int rr = 0; rr < 2; ++rr) {
    int d = rr * 32 + (tid >> 3);
    int t0 = (tid & 7) * 8;
    u16x8 v;
#pragma unroll
    for (int j = 0; j < 8; ++j) v[j] = tile[t0 + j][d];
    *(u16x8*)&vt[((size_t)(b * 16 + h) * 64 + d) * 1024 + tt * 64 + t0] = v;
  }
}

// ---------------- lambda_full scalar ----------------
__global__ void k_lambda(const float* lq1, const float* lq2,
                         const float* lk1, const float* lk2, float* out) {
  int i = threadIdx.x;
  float a = 0.f, b = 0.f;
  if (i < 32) { a = lq1[i] * lk1[i]; b = lq2[i] * lk2[i]; }
#pragma unroll
  for (int s = 1; s < 64; s <<= 1) { a += __shfl_xor(a, s); b += __shfl_xor(b, s); }
  if (i == 0) out[0] = __expf(a) - __expf(b) + 0.2f;
}

// ---------------- bf16 GEMM: 2-phase counted-vmcnt double buffer ----------
template <bool OUT_F32>
__global__ __launch_bounds__(256) void k_gemm(const u16* __restrict__ A,
                                              const u16* __restrict__ Bt,
                                              void* __restrict__ Cout,
                                              int M, int N, int K) {
  __shared__ __align__(16) u16 As[2][128 * 32];
  __shared__ __align__(16) u16 Bs[2][128 * 32];
  int tid = threadIdx.x;
  int nbn = N >> 7;
  int wg = ((int)blockIdx.x & 7) * ((int)gridDim.x >> 3) + ((int)blockIdx.x >> 3);
  int bm = wg / nbn, bn = wg % nbn;
  int m0 = bm << 7, n0 = bn << 7;
  int lane = tid & 63, w = tid >> 6, wm = w >> 1, wn = w & 1;
  int lr = lane & 15, lg = lane >> 4;
  const u16* pA0; const u16* pA1; const u16* pB0; const u16* pB1;
  {
    int i0 = tid, i1 = tid + 256;
    int r0 = i0 >> 2, s80 = (i0 & 3) ^ ((r0 >> 1) & 3);
    int r1 = i1 >> 2, s81 = (i1 & 3) ^ ((r1 >> 1) & 3);
    pA0 = &A[(size_t)(m0 + r0) * K + s80 * 8];
    pA1 = &A[(size_t)(m0 + r1) * K + s81 * 8];
    pB0 = &Bt[(size_t)(n0 + r0) * K + s80 * 8];
    pB1 = &Bt[(size_t)(n0 + r1) * K + s81 * 8];
  }
  f32x4 acc[4][4] = {};
  auto stage = [&](int kt, int buf) {
    gld16(pA0 + kt, &As[buf][tid * 8]);
    gld16(pA1 + kt, &As[buf][(tid + 256) * 8]);
    gld16(pB0 + kt, &Bs[buf][tid * 8]);
    gld16(pB1 + kt, &Bs[buf][(tid + 256) * 8]);
  };
  int NK = K >> 5;
  stage(0, 0);
  for (int ki = 0; ki < NK; ++ki) {
    int cur = ki & 1;
    if (ki + 1 < NK) {
      stage((ki + 1) << 5, cur ^ 1);
      asm volatile("s_waitcnt vmcnt(4)" ::: "memory");
    } else {
      asm volatile("s_waitcnt vmcnt(0)" ::: "memory");
    }
    __builtin_amdgcn_s_barrier();
    __builtin_amdgcn_sched_barrier(0);
    bf16x8 af[4], bfr[4];
#pragma unroll
    for (int m = 0; m < 4; ++m) {
      int r = wm * 64 + m * 16 + lr;
      int c8 = lg ^ ((r >> 1) & 3);
      af[m] = *(const bf16x8*)&As[cur][r * 32 + c8 * 8];
    }
#pragma unroll
    for (int n = 0; n < 4; ++n) {
      int r = wn * 64 + n * 16 + lr;
      int c8 = lg ^ ((r >> 1) & 3);
      bfr[n] = *(const bf16x8*)&Bs[cur][r * 32 + c8 * 8];
    }
#pragma unroll
    for (int m = 0; m < 4; ++m)
#pragma unroll
      for (int n = 0; n < 4; ++n)
        acc[m][n] = __builtin_amdgcn_mfma_f32_16x16x32_bf16(af[m], bfr[n], acc[m][n], 0, 0, 0);
    __builtin_amdgcn_sched_barrier(0);
    __builtin_amdgcn_s_barrier();
  }
#pragma unroll
  for (int m = 0; m < 4; ++m)
#pragma unroll
    for (int r = 0; r < 4; ++r) {
      int gr = m0 + wm * 64 + m * 16 + lg * 4 + r;
#pragma unroll
      for (int n = 0; n < 4; ++n) {
        int gc = n0 + wn * 64 + n * 16 + lr;
        if (OUT_F32) ((float*)Cout)[(size_t)gr * N + gc] = acc[m][n][r];
        else ((u16*)Cout)[(size_t)gr * N + gc] = f2bf(acc[m][n][r]);
      }
    }
}

// ---------------- differential flash attention (merged dual-q-block) --------
// grid 512; CU c gets blocks c & c+256 -> p and 7-p of the SAME (b,h)
// (25 tiles/CU, perfectly balanced, K/V L1/L2 reuse). Each block processes
// q-blocks qbS=p and qbL=15-p CONCURRENTLY in one k-loop over tiles 0..qbL:
// shared K/V staging, small block active while t<=qbS. All per-q-block state
// compile-time indexed (rule #20).
__global__ __launch_bounds__(256) void k_diffattn(const u16* __restrict__ qkv,
                                                  const u16* __restrict__ vt,
                                                  const float* __restrict__ lam_p,
                                                  const float* __restrict__ gamma,
                                                  u16* __restrict__ attn_out) {
  __shared__ __align__(16) u16 Ks[2][2][64 * 32];     // 16 KB
  __shared__ __align__(16) u16 Vs[2][64 * 64];        // 16 KB
  __shared__ __align__(16) u16 Ps[2][4][2][16 * 72];  // 36 KB  [qi][wave][mat]
  int bid = blockIdx.x;
  int kk8 = (bid & 255) >> 6;
  int p = (bid >> 8) ? (7 - kk8) : kk8;
  int b = (bid >> 4) & 3, h = bid & 15;
  int qbS = p, qbL = 15 - p;
  int tid = threadIdx.x, lane = tid & 63, w = tid >> 6;
  int lr = lane & 15, lg = lane >> 4;
  int g1 = 2 * h, g2 = g1 + 1;
  float lam = *lam_p;
  const float cexp = 0.045084222f;  // log2(e)/32
  f32x4 zero = {0.f, 0.f, 0.f, 0.f};

  // hoisted staging pointers
  const u16* pK1; const u16* pK2;
  {
    int r = tid >> 2, c8 = tid & 3;
    int s8 = c8 ^ ((r >> 1) & 3);
    size_t krow = (size_t)(b * 1024 + r) * 3072 + 1024;
    pK1 = qkv + krow + g1 * 32 + s8 * 8;
    pK2 = qkv + krow + g2 * 32 + s8 * 8;
  }
  const u16* pV0; const u16* pV1;
  {
    const u16* vbase = vt + ((size_t)(b * 16 + h) * 64) * 1024;
    int d0 = tid >> 3, o0 = (tid & 7) ^ (d0 & 7);
    pV0 = vbase + (size_t)d0 * 1024 + o0 * 8;
    pV1 = vbase + (size_t)(d0 + 32) * 1024 + o0 * 8;
  }
  auto stage = [&](int s0, int buf) {
    gld16(pK1 + (size_t)s0 * 3072, &Ks[buf][0][tid * 8]);
    gld16(pK2 + (size_t)s0 * 3072, &Ks[buf][1][tid * 8]);
    gld16(pV0 + s0, &Vs[buf][tid * 8]);
    gld16(pV1 + s0, &Vs[buf][(tid + 256) * 8]);
  };

  // per-q-block state (compile-time indexed)
  bf16x8 qf1[2], qf2[2];
  f32x4 o1[2][4] = {}, o2[2][4] = {};
  float l1[2][4] = {}, l2[2][4] = {};
  int q0v[2] = {qbS * 64, qbL * 64};
  int qg[2] = {q0v[0] + w * 16 + lg * 4, q0v[1] + w * 16 + lg * 4};
  {
    size_t qrowS = (size_t)(b * 1024 + q0v[0] + w * 16 + lr) * 3072;
    size_t qrowL = (size_t)(b * 1024 + q0v[1] + w * 16 + lr) * 3072;
    qf1[0] = *(const bf16x8*)&qkv[qrowS + g1 * 32 + lg * 8];
    qf2[0] = *(const bf16x8*)&qkv[qrowS + g2 * 32 + lg * 8];
    qf1[1] = *(const bf16x8*)&qkv[qrowL + g1 * 32 + lg * 8];
    qf2[1] = *(const bf16x8*)&qkv[qrowL + g2 * 32 + lg * 8];
  }
  u16* P1[2] = {&Ps[0][w][0][0], &Ps[1][w][0][0]};
  u16* P2[2] = {&Ps[0][w][1][0], &Ps[1][w][1][0]};

  auto qk_sm = [&](auto qc, auto mk, int cur, int s0) {
    constexpr int qi = decltype(qc)::value;
    f32x4 s1[4], s2[4];
#pragma unroll
    for (int ni = 0; ni < 4; ++ni) {
      int rk = ni * 16 + lr;
      int c8 = lg ^ ((rk >> 1) & 3);
      bf16x8 kf1 = *(const bf16x8*)&Ks[cur][0][rk * 32 + c8 * 8];
      bf16x8 kf2 = *(const bf16x8*)&Ks[cur][1][rk * 32 + c8 * 8];
      s1[ni] = __builtin_amdgcn_mfma_f32_16x16x32_bf16(qf1[qi], kf1, zero, 0, 0, 0);
      s2[ni] = __builtin_amdgcn_mfma_f32_16x16x32_bf16(qf2[qi], kf2, zero, 0, 0, 0);
    }
#pragma unroll
    for (int ni = 0; ni < 4; ++ni) {
      int sg = s0 + ni * 16 + lr;
#pragma unroll
      for (int r = 0; r < 4; ++r) {
        float v1 = fexp2(s1[ni][r] * cexp);
        float v2 = fexp2(s2[ni][r] * cexp);
        if constexpr (decltype(mk)::value) {
          if (sg > qg[qi] + r) { v1 = 0.f; v2 = 0.f; }
        }
        l1[qi][r] += v1; l2[qi][r] += v2;
        P1[qi][(lg * 4 + r) * 72 + ni * 16 + lr] = f2bf_fast(v1);
        P2[qi][(lg * 4 + r) * 72 + ni * 16 + lr] = f2bf_fast(v2);
      }
    }
  };
  auto pv = [&](auto qc, int cur) {
    constexpr int qi = decltype(qc)::value;
#pragma unroll
    for (int kk = 0; kk < 2; ++kk) {
      bf16x8 pa1 = *(const bf16x8*)&P1[qi][lr * 72 + kk * 32 + lg * 8];
      bf16x8 pa2 = *(const bf16x8*)&P2[qi][lr * 72 + kk * 32 + lg * 8];
#pragma unroll
      for (int ni = 0; ni < 4; ++ni) {
        int d = ni * 16 + lr;
        int c8 = (kk * 4 + lg) ^ (d & 7);
        bf16x8 vb = *(const bf16x8*)&Vs[cur][d * 64 + c8 * 8];
        o1[qi][ni] = __builtin_amdgcn_mfma_f32_16x16x32_bf16(pa1, vb, o1[qi][ni], 0, 0, 0);
        o2[qi][ni] = __builtin_amdgcn_mfma_f32_16x16x32_bf16(pa2, vb, o2[qi][ni], 0, 0, 0);
      }
    }
  };

  auto step = [&](int t, auto doS, auto mkS, auto mkL) {
    int cur = t & 1;
    if (t < qbL) {
      stage((t + 1) * 64, cur ^ 1);
      asm volatile("s_waitcnt vmcnt(4)" ::: "memory");
    } else {
      asm volatile("s_waitcnt vmcnt(0)" ::: "memory");
    }
    __builtin_amdgcn_s_barrier();
    __builtin_amdgcn_sched_barrier(0);
    int s0 = t * 64;
    if constexpr (decltype(doS)::value) qk_sm(IC<0>{}, mkS, cur, s0);
    qk_sm(IC<1>{}, mkL, cur, s0);
    if constexpr (decltype(doS)::value) pv(IC<0>{}, cur);
    pv(IC<1>{}, cur);
    __builtin_amdgcn_sched_barrier(0);
    __builtin_amdgcn_s_barrier();
  };

  stage(0, 0);
  int t = 0;
  for (; t < qbS; ++t) step(t, BC<true>{}, BC<false>{}, BC<false>{});
  step(t, BC<true>{}, BC<true>{}, BC<false>{});  // t == qbS: diag for S
  ++t;
  for (; t < qbL; ++t) step(t, BC<false>{}, BC<false>{}, BC<false>{});
  step(t, BC<false>{}, BC<false>{}, BC<true>{}); // t == qbL: diag for L

  // epilogue per q-block
  auto epi = [&](auto qc) {
    constexpr int qi = decltype(qc)::value;
#pragma unroll
    for (int r = 0; r < 4; ++r) {
      float a = l1[qi][r], c = l2[qi][r];
      a += __shfl_xor(a, 1); a += __shfl_xor(a, 2);
      a += __shfl_xor(a, 4); a += __shfl_xor(a, 8);
      c += __shfl_xor(c, 1); c += __shfl_xor(c, 2);
      c += __shfl_xor(c, 4); c += __shfl_xor(c, 8);
      l1[qi][r] = a; l2[qi][r] = c;
    }
    float val[4][4];
#pragma unroll
    for (int ni = 0; ni < 4; ++ni)
#pragma unroll
      for (int r = 0; r < 4; ++r)
        val[ni][r] = o1[qi][ni][r] * (1.f / l1[qi][r]) - lam * (o2[qi][ni][r] * (1.f / l2[qi][r]));
#pragma unroll
    for (int r = 0; r < 4; ++r) {
      float ss = 0.f;
#pragma unroll
      for (int ni = 0; ni < 4; ++ni) ss += val[ni][r] * val[ni][r];
      ss += __shfl_xor(ss, 1); ss += __shfl_xor(ss, 2);
      ss += __shfl_xor(ss, 4); ss += __shfl_xor(ss, 8);
      float sc = rsqrtf(ss * (1.f / 64.f) + 1e-5f) * 0.8f;
#pragma unroll
      for (int ni = 0; ni < 4; ++ni) val[ni][r] *= sc;
    }
#pragma unroll
    for (int ni = 0; ni < 4; ++ni) {
      int d = ni * 16 + lr;
      float g = gamma[d];
#pragma unroll
      for (int r = 0; r < 4; ++r) {
        int trow = q0v[qi] + w * 16 + lg * 4 + r;
        attn_out[(size_t)(b * 1024 + trow) * 1024 + h * 64 + d] = f2bf(val[ni][r] * g);
      }
    }
  };
  epi(IC<0>{});
  epi(IC<1>{});
}

// ---------------- launch ----------------
extern "C" void kernel_launch(void* const* d_in, const int* in_sizes, int n_in,
                              void* d_out, int out_size, void* d_ws, size_t ws_size,
                              hipStream_t stream) {
  const float* x   = (const float*)d_in[0];
  const float* wa  = (const float*)d_in[1];
  const float* wp  = (const float*)d_in[2];
  const float* lq1 = (const float*)d_in[3];
  const float* lq2 = (const float*)d_in[4];
  const float* lk1 = (const float*)d_in[5];
  const float* lk2 = (const float*)d_in[6];
  const float* gam = (const float*)d_in[7];
  float* out = (float*)d_out;

  char* ws = (char*)d_ws;
  u16* xb   = (u16*)(ws);                        // 8 MiB  [4096][1024]
  u16* wab  = (u16*)(ws + (8ull << 20));         // 6 MiB  [3072][1024] (w_attn^T)
  u16* wpb  = (u16*)(ws + (14ull << 20));        // 2 MiB  [1024][1024] (w_proj^T)
  u16* qkv  = (u16*)(ws + (16ull << 20));        // 24 MiB [4096][3072]
  u16* vt   = (u16*)(ws + (40ull << 20));        // 8 MiB  [4][16][64][1024]
  u16* aout = (u16*)(ws + (48ull << 20));        // 8 MiB  [4096][1024]
  float* lam = (float*)(ws + (56ull << 20));     // 4 B

  k_cast<<<4096, 256, 0, stream>>>(x, xb, 1024 * 1024);
  k_transpose_cast<<<dim3(16, 48), 256, 0, stream>>>(wa, wab, 1024, 3072);
  k_transpose_cast<<<dim3(16, 16), 256, 0, stream>>>(wp, wpb, 1024, 1024);
  k_lambda<<<1, 64, 0, stream>>>(lq1, lq2, lk1, lk2, lam);
  k_gemm<false><<<32 * 24, 256, 0, stream>>>(xb, wab, qkv, 4096, 3072, 1024);
  k_vtrans<<<1024, 256, 0, stream>>>(qkv, vt);
  k_diffattn<<<512, 256, 0, stream>>>(qkv, vt, lam, gam, aout);
  k_gemm<true><<<32 * 8, 256, 0, stream>>>(aout, wpb, out, 4096, 1024, 1024);
}

// Round 8
// 189.398 us; speedup vs baseline: 1.0806x; 1.0806x over previous
//
#include <hip/hip_runtime.h>

typedef unsigned short u16;
typedef unsigned int u32;
typedef __bf16 bf16x8 __attribute__((ext_vector_type(8)));
typedef float f32x4 __attribute__((ext_vector_type(4)));
typedef u16 u16x8 __attribute__((ext_vector_type(8)));
typedef u16 u16x4 __attribute__((ext_vector_type(4)));

#define DEV static __device__ __forceinline__

template <bool B> struct BC { static constexpr bool value = B; };

DEV u16 f2bf(float f) {
  unsigned u = __builtin_bit_cast(unsigned, f);
  u += 0x7fffu + ((u >> 16) & 1u);
  return (u16)(u >> 16);
}
DEV u16 f2bf_fast(float f) {
  unsigned u = __builtin_bit_cast(unsigned, f);
  return (u16)((u + 0x8000u) >> 16);
}
DEV float fexp2(float x) {
  float r;
  asm("v_exp_f32 %0, %1" : "=v"(r) : "v"(x));
  return r;
}

DEV void gld16(const void* g, void* l) {
  __builtin_amdgcn_global_load_lds((__attribute__((address_space(1))) void*)(g),
                                   (__attribute__((address_space(3))) void*)(l),
                                   16, 0, 0);
}

// ---------------- cast fp32 -> bf16 ----------------
__global__ __launch_bounds__(256) void k_cast(const float* __restrict__ in,
                                              u16* __restrict__ out, int n4) {
  int i = blockIdx.x * 256 + threadIdx.x;
  if (i >= n4) return;
  float4 v = ((const float4*)in)[i];
  u16x4 r = { f2bf(v.x), f2bf(v.y), f2bf(v.z), f2bf(v.w) };
  ((u16x4*)out)[i] = r;
}

// ---------------- cast + transpose ----------------
__global__ __launch_bounds__(256) void k_transpose_cast(const float* __restrict__ in,
                                                        u16* __restrict__ out,
                                                        int R, int Cc) {
  __shared__ u16 tile[64][65];
  int r0 = blockIdx.x * 64, c0 = blockIdx.y * 64;
  int tid = threadIdx.x;
#pragma unroll
  for (int rr = 0; rr < 4; ++rr) {
    int r = rr * 16 + (tid >> 4);
    int c = (tid & 15) * 4;
    float4 v = *(const float4*)&in[(size_t)(r0 + r) * Cc + c0 + c];
    tile[r][c + 0] = f2bf(v.x); tile[r][c + 1] = f2bf(v.y);
    tile[r][c + 2] = f2bf(v.z); tile[r][c + 3] = f2bf(v.w);
  }
  __syncthreads();
#pragma unroll
  for (int rr = 0; rr < 2; ++rr) {
    int cr = rr * 32 + (tid >> 3);
    int rc = (tid & 7) * 8;
    u16x8 v;
#pragma unroll
    for (int j = 0; j < 8; ++j) v[j] = tile[rc + j][cr];
    *(u16x8*)&out[(size_t)(c0 + cr) * R + r0 + rc] = v;
  }
}

// -------- extract V from qkv, transpose: vt[b][h][d=64][t=1024] bf16 --------
__global__ __launch_bounds__(256) void k_vtrans(const u16* __restrict__ qkv,
                                                u16* __restrict__ vt) {
  __shared__ u16 tile[64][65];
  int bid = blockIdx.x;
  int b = bid >> 8, h = (bid >> 4) & 15, tt = bid & 15;
  int tid = threadIdx.x;
#pragma unroll
  for (int rr = 0; rr < 2; ++rr) {
    int tl = rr * 32 + (tid >> 3);
    int d0 = (tid & 7) * 8;
    u16x8 v = *(const u16x8*)&qkv[(size_t)(b * 1024 + tt * 64 + tl) * 3072 + 2048 + h * 64 + d0];
#pragma unroll
    for (int j = 0; j < 8; ++j) tile[tl][d0 + j] = v[j];
  }
  __syncthreads();
#pragma unroll
  for (int rr = 0; rr < 2; ++rr) {
    int d = rr * 32 + (tid >> 3);
    int t0 = (tid & 7) * 8;
    u16x8 v;
#pragma unroll
    for (int j = 0; j < 8; ++j) v[j] = tile[t0 + j][d];
    *(u16x8*)&vt[((size_t)(b * 16 + h) * 64 + d) * 1024 + tt * 64 + t0] = v;
  }
}

// ---------------- lambda_full scalar ----------------
__global__ void k_lambda(const float* lq1, const float* lq2,
                         const float* lk1, const float* lk2, float* out) {
  int i = threadIdx.x;
  float a = 0.f, b = 0.f;
  if (i < 32) { a = lq1[i] * lk1[i]; b = lq2[i] * lk2[i]; }
#pragma unroll
  for (int s = 1; s < 64; s <<= 1) { a += __shfl_xor(a, s); b += __shfl_xor(b, s); }
  if (i == 0) out[0] = __expf(a) - __expf(b) + 0.2f;
}

// ---------------- bf16 GEMM: 2-phase counted-vmcnt double buffer ----------
template <bool OUT_F32>
__global__ __launch_bounds__(256) void k_gemm(const u16* __restrict__ A,
                                              const u16* __restrict__ Bt,
                                              void* __restrict__ Cout,
                                              int M, int N, int K) {
  __shared__ __align__(16) u16 As[2][128 * 32];
  __shared__ __align__(16) u16 Bs[2][128 * 32];
  int tid = threadIdx.x;
  int nbn = N >> 7;
  int wg = ((int)blockIdx.x & 7) * ((int)gridDim.x >> 3) + ((int)blockIdx.x >> 3);
  int bm = wg / nbn, bn = wg % nbn;
  int m0 = bm << 7, n0 = bn << 7;
  int lane = tid & 63, w = tid >> 6, wm = w >> 1, wn = w & 1;
  int lr = lane & 15, lg = lane >> 4;
  const u16* pA0; const u16* pA1; const u16* pB0; const u16* pB1;
  {
    int i0 = tid, i1 = tid + 256;
    int r0 = i0 >> 2, s80 = (i0 & 3) ^ ((r0 >> 1) & 3);
    int r1 = i1 >> 2, s81 = (i1 & 3) ^ ((r1 >> 1) & 3);
    pA0 = &A[(size_t)(m0 + r0) * K + s80 * 8];
    pA1 = &A[(size_t)(m0 + r1) * K + s81 * 8];
    pB0 = &Bt[(size_t)(n0 + r0) * K + s80 * 8];
    pB1 = &Bt[(size_t)(n0 + r1) * K + s81 * 8];
  }
  f32x4 acc[4][4] = {};
  auto stage = [&](int kt, int buf) {
    gld16(pA0 + kt, &As[buf][tid * 8]);
    gld16(pA1 + kt, &As[buf][(tid + 256) * 8]);
    gld16(pB0 + kt, &Bs[buf][tid * 8]);
    gld16(pB1 + kt, &Bs[buf][(tid + 256) * 8]);
  };
  int NK = K >> 5;
  stage(0, 0);
  for (int ki = 0; ki < NK; ++ki) {
    int cur = ki & 1;
    if (ki + 1 < NK) {
      stage((ki + 1) << 5, cur ^ 1);
      asm volatile("s_waitcnt vmcnt(4)" ::: "memory");
    } else {
      asm volatile("s_waitcnt vmcnt(0)" ::: "memory");
    }
    __builtin_amdgcn_s_barrier();
    __builtin_amdgcn_sched_barrier(0);
    bf16x8 af[4], bfr[4];
#pragma unroll
    for (int m = 0; m < 4; ++m) {
      int r = wm * 64 + m * 16 + lr;
      int c8 = lg ^ ((r >> 1) & 3);
      af[m] = *(const bf16x8*)&As[cur][r * 32 + c8 * 8];
    }
#pragma unroll
    for (int n = 0; n < 4; ++n) {
      int r = wn * 64 + n * 16 + lr;
      int c8 = lg ^ ((r >> 1) & 3);
      bfr[n] = *(const bf16x8*)&Bs[cur][r * 32 + c8 * 8];
    }
#pragma unroll
    for (int m = 0; m < 4; ++m)
#pragma unroll
      for (int n = 0; n < 4; ++n)
        acc[m][n] = __builtin_amdgcn_mfma_f32_16x16x32_bf16(af[m], bfr[n], acc[m][n], 0, 0, 0);
    __builtin_amdgcn_sched_barrier(0);
    __builtin_amdgcn_s_barrier();
  }
#pragma unroll
  for (int m = 0; m < 4; ++m)
#pragma unroll
    for (int r = 0; r < 4; ++r) {
      int gr = m0 + wm * 64 + m * 16 + lg * 4 + r;
#pragma unroll
      for (int n = 0; n < 4; ++n) {
        int gc = n0 + wn * 64 + n * 16 + lr;
        if (OUT_F32) ((float*)Cout)[(size_t)gr * N + gc] = acc[m][n][r];
        else ((u16*)Cout)[(size_t)gr * N + gc] = f2bf(acc[m][n][r]);
      }
    }
}

// ---------------- differential flash attention (LPT dynamic balance) --------
// grid 1024 = one q-block per block; qb = 15 - (bid>>6) puts HEAVY blocks
// first in dispatch order (LPT) so dynamic refill balances CUs without any
// CU-assignment assumption (R7 lesson). LDS 50 KB -> 3 blocks/CU resident:
// independent blocks overlap each other's serial QK->softmax->PV chains.
__global__ __launch_bounds__(256) void k_diffattn(const u16* __restrict__ qkv,
                                                  const u16* __restrict__ vt,
                                                  const float* __restrict__ lam_p,
                                                  const float* __restrict__ gamma,
                                                  u16* __restrict__ attn_out) {
  __shared__ __align__(16) u16 Ks[2][2][64 * 32];  // 16 KB
  __shared__ __align__(16) u16 Vs[2][64 * 64];     // 16 KB
  __shared__ __align__(16) u16 Ps[4][2][16 * 72];  // 18 KB
  int bid = blockIdx.x;
  int qb = 15 - (bid >> 6);
  int b = (bid >> 4) & 3, h = bid & 15;
  int tid = threadIdx.x, lane = tid & 63, w = tid >> 6;
  int lr = lane & 15, lg = lane >> 4;
  int g1 = 2 * h, g2 = g1 + 1;
  float lam = *lam_p;
  const float cexp = 0.045084222f;  // log2(e)/32
  f32x4 zero = {0.f, 0.f, 0.f, 0.f};
  u16* P1 = &Ps[w][0][0];
  u16* P2 = &Ps[w][1][0];

  // hoisted staging pointers
  const u16* pK1; const u16* pK2;
  {
    int r = tid >> 2, c8 = tid & 3;
    int s8 = c8 ^ ((r >> 1) & 3);
    size_t krow = (size_t)(b * 1024 + r) * 3072 + 1024;
    pK1 = qkv + krow + g1 * 32 + s8 * 8;
    pK2 = qkv + krow + g2 * 32 + s8 * 8;
  }
  const u16* pV0; const u16* pV1;
  {
    const u16* vbase = vt + ((size_t)(b * 16 + h) * 64) * 1024;
    int d0 = tid >> 3, o0 = (tid & 7) ^ (d0 & 7);
    pV0 = vbase + (size_t)d0 * 1024 + o0 * 8;
    pV1 = vbase + (size_t)(d0 + 32) * 1024 + o0 * 8;
  }

  auto stage = [&](int s0, int buf) {
    gld16(pK1 + (size_t)s0 * 3072, &Ks[buf][0][tid * 8]);
    gld16(pK2 + (size_t)s0 * 3072, &Ks[buf][1][tid * 8]);
    gld16(pV0 + s0, &Vs[buf][tid * 8]);
    gld16(pV1 + s0, &Vs[buf][(tid + 256) * 8]);
  };

  int q0 = qb * 64;
  size_t qrow = (size_t)(b * 1024 + q0 + w * 16 + lr);
  bf16x8 qf1 = *(const bf16x8*)&qkv[qrow * 3072 + g1 * 32 + lg * 8];
  bf16x8 qf2 = *(const bf16x8*)&qkv[qrow * 3072 + g2 * 32 + lg * 8];
  f32x4 o1[4] = {}, o2[4] = {};
  float l1[4] = {}, l2[4] = {};
  int qg_base = q0 + w * 16 + lg * 4;

  auto tile = [&](int cur, int s0, auto mk) {
    f32x4 s1[4], s2[4];
#pragma unroll
    for (int ni = 0; ni < 4; ++ni) {
      int rk = ni * 16 + lr;
      int c8 = lg ^ ((rk >> 1) & 3);
      bf16x8 kf1 = *(const bf16x8*)&Ks[cur][0][rk * 32 + c8 * 8];
      bf16x8 kf2 = *(const bf16x8*)&Ks[cur][1][rk * 32 + c8 * 8];
      s1[ni] = __builtin_amdgcn_mfma_f32_16x16x32_bf16(qf1, kf1, zero, 0, 0, 0);
      s2[ni] = __builtin_amdgcn_mfma_f32_16x16x32_bf16(qf2, kf2, zero, 0, 0, 0);
    }
#pragma unroll
    for (int ni = 0; ni < 4; ++ni) {
      int sg = s0 + ni * 16 + lr;
#pragma unroll
      for (int r = 0; r < 4; ++r) {
        float v1 = fexp2(s1[ni][r] * cexp);
        float v2 = fexp2(s2[ni][r] * cexp);
        if constexpr (decltype(mk)::value) {
          if (sg > qg_base + r) { v1 = 0.f; v2 = 0.f; }
        }
        l1[r] += v1; l2[r] += v2;
        P1[(lg * 4 + r) * 72 + ni * 16 + lr] = f2bf_fast(v1);
        P2[(lg * 4 + r) * 72 + ni * 16 + lr] = f2bf_fast(v2);
      }
    }
#pragma unroll
    for (int kk = 0; kk < 2; ++kk) {
      bf16x8 pa1 = *(const bf16x8*)&P1[lr * 72 + kk * 32 + lg * 8];
      bf16x8 pa2 = *(const bf16x8*)&P2[lr * 72 + kk * 32 + lg * 8];
#pragma unroll
      for (int ni = 0; ni < 4; ++ni) {
        int d = ni * 16 + lr;
        int c8 = (kk * 4 + lg) ^ (d & 7);
        bf16x8 vb = *(const bf16x8*)&Vs[cur][d * 64 + c8 * 8];
        o1[ni] = __builtin_amdgcn_mfma_f32_16x16x32_bf16(pa1, vb, o1[ni], 0, 0, 0);
        o2[ni] = __builtin_amdgcn_mfma_f32_16x16x32_bf16(pa2, vb, o2[ni], 0, 0, 0);
      }
    }
  };

  stage(0, 0);
  for (int t = 0; t < qb; ++t) {
    int cur = t & 1;
    stage((t + 1) * 64, cur ^ 1);
    asm volatile("s_waitcnt vmcnt(4)" ::: "memory");
    __builtin_amdgcn_s_barrier();
    __builtin_amdgcn_sched_barrier(0);
    tile(cur, t * 64, BC<false>{});
    __builtin_amdgcn_sched_barrier(0);
    __builtin_amdgcn_s_barrier();
  }
  asm volatile("s_waitcnt vmcnt(0)" ::: "memory");
  __builtin_amdgcn_s_barrier();
  __builtin_amdgcn_sched_barrier(0);
  tile(qb & 1, q0, BC<true>{});

  // epilogue
#pragma unroll
  for (int r = 0; r < 4; ++r) {
    l1[r] += __shfl_xor(l1[r], 1); l1[r] += __shfl_xor(l1[r], 2);
    l1[r] += __shfl_xor(l1[r], 4); l1[r] += __shfl_xor(l1[r], 8);
    l2[r] += __shfl_xor(l2[r], 1); l2[r] += __shfl_xor(l2[r], 2);
    l2[r] += __shfl_xor(l2[r], 4); l2[r] += __shfl_xor(l2[r], 8);
  }
  float val[4][4];
#pragma unroll
  for (int ni = 0; ni < 4; ++ni)
#pragma unroll
    for (int r = 0; r < 4; ++r)
      val[ni][r] = o1[ni][r] * (1.f / l1[r]) - lam * (o2[ni][r] * (1.f / l2[r]));
#pragma unroll
  for (int r = 0; r < 4; ++r) {
    float ss = 0.f;
#pragma unroll
    for (int ni = 0; ni < 4; ++ni) ss += val[ni][r] * val[ni][r];
    ss += __shfl_xor(ss, 1); ss += __shfl_xor(ss, 2);
    ss += __shfl_xor(ss, 4); ss += __shfl_xor(ss, 8);
    float sc = rsqrtf(ss * (1.f / 64.f) + 1e-5f) * 0.8f;
#pragma unroll
    for (int ni = 0; ni < 4; ++ni) val[ni][r] *= sc;
  }
#pragma unroll
  for (int ni = 0; ni < 4; ++ni) {
    int d = ni * 16 + lr;
    float g = gamma[d];
#pragma unroll
    for (int r = 0; r < 4; ++r) {
      int trow = q0 + w * 16 + lg * 4 + r;
      attn_out[(size_t)(b * 1024 + trow) * 1024 + h * 64 + d] = f2bf(val[ni][r] * g);
    }
  }
}

// ---------------- launch ----------------
extern "C" void kernel_launch(void* const* d_in, const int* in_sizes, int n_in,
                              void* d_out, int out_size, void* d_ws, size_t ws_size,
                              hipStream_t stream) {
  const float* x   = (const float*)d_in[0];
  const float* wa  = (const float*)d_in[1];
  const float* wp  = (const float*)d_in[2];
  const float* lq1 = (const float*)d_in[3];
  const float* lq2 = (const float*)d_in[4];
  const float* lk1 = (const float*)d_in[5];
  const float* lk2 = (const float*)d_in[6];
  const float* gam = (const float*)d_in[7];
  float* out = (float*)d_out;

  char* ws = (char*)d_ws;
  u16* xb   = (u16*)(ws);                        // 8 MiB  [4096][1024]
  u16* wab  = (u16*)(ws + (8ull << 20));         // 6 MiB  [3072][1024] (w_attn^T)
  u16* wpb  = (u16*)(ws + (14ull << 20));        // 2 MiB  [1024][1024] (w_proj^T)
  u16* qkv  = (u16*)(ws + (16ull << 20));        // 24 MiB [4096][3072]
  u16* vt   = (u16*)(ws + (40ull << 20));        // 8 MiB  [4][16][64][1024]
  u16* aout = (u16*)(ws + (48ull << 20));        // 8 MiB  [4096][1024]
  float* lam = (float*)(ws + (56ull << 20));     // 4 B

  k_cast<<<4096, 256, 0, stream>>>(x, xb, 1024 * 1024);
  k_transpose_cast<<<dim3(16, 48), 256, 0, stream>>>(wa, wab, 1024, 3072);
  k_transpose_cast<<<dim3(16, 16), 256, 0, stream>>>(wp, wpb, 1024, 1024);
  k_lambda<<<1, 64, 0, stream>>>(lq1, lq2, lk1, lk2, lam);
  k_gemm<false><<<32 * 24, 256, 0, stream>>>(xb, wab, qkv, 4096, 3072, 1024);
  k_vtrans<<<1024, 256, 0, stream>>>(qkv, vt);
  k_diffattn<<<1024, 256, 0, stream>>>(qkv, vt, lam, gam, aout);
  k_gemm<true><<<32 * 8, 256, 0, stream>>>(aout, wpb, out, 4096, 1024, 1024);
}

// Round 9
// 186.272 us; speedup vs baseline: 1.0988x; 1.0168x over previous
//
#include <hip/hip_runtime.h>

typedef unsigned short u16;
typedef unsigned int u32;
typedef __bf16 bf16x8 __attribute__((ext_vector_type(8)));
typedef float f32x4 __attribute__((ext_vector_type(4)));
typedef u16 u16x8 __attribute__((ext_vector_type(8)));
typedef u16 u16x4 __attribute__((ext_vector_type(4)));

#define DEV static __device__ __forceinline__

template <bool B> struct BC { static constexpr bool value = B; };

DEV u16 f2bf(float f) {
  unsigned u = __builtin_bit_cast(unsigned, f);
  u += 0x7fffu + ((u >> 16) & 1u);
  return (u16)(u >> 16);
}
DEV u16 f2bf_fast(float f) {
  unsigned u = __builtin_bit_cast(unsigned, f);
  return (u16)((u + 0x8000u) >> 16);
}
DEV float fexp2(float x) {
  float r;
  asm("v_exp_f32 %0, %1" : "=v"(r) : "v"(x));
  return r;
}

DEV void gld16(const void* g, void* l) {
  __builtin_amdgcn_global_load_lds((__attribute__((address_space(1))) void*)(g),
                                   (__attribute__((address_space(3))) void*)(l),
                                   16, 0, 0);
}

// ---------------- cast fp32 -> bf16 ----------------
__global__ __launch_bounds__(256) void k_cast(const float* __restrict__ in,
                                              u16* __restrict__ out, int n4) {
  int i = blockIdx.x * 256 + threadIdx.x;
  if (i >= n4) return;
  float4 v = ((const float4*)in)[i];
  u16x4 r = { f2bf(v.x), f2bf(v.y), f2bf(v.z), f2bf(v.w) };
  ((u16x4*)out)[i] = r;
}

// ---------------- cast + transpose ----------------
__global__ __launch_bounds__(256) void k_transpose_cast(const float* __restrict__ in,
                                                        u16* __restrict__ out,
                                                        int R, int Cc) {
  __shared__ u16 tile[64][65];
  int r0 = blockIdx.x * 64, c0 = blockIdx.y * 64;
  int tid = threadIdx.x;
#pragma unroll
  for (int rr = 0; rr < 4; ++rr) {
    int r = rr * 16 + (tid >> 4);
    int c = (tid & 15) * 4;
    float4 v = *(const float4*)&in[(size_t)(r0 + r) * Cc + c0 + c];
    tile[r][c + 0] = f2bf(v.x); tile[r][c + 1] = f2bf(v.y);
    tile[r][c + 2] = f2bf(v.z); tile[r][c + 3] = f2bf(v.w);
  }
  __syncthreads();
#pragma unroll
  for (int rr = 0; rr < 2; ++rr) {
    int cr = rr * 32 + (tid >> 3);
    int rc = (tid & 7) * 8;
    u16x8 v;
#pragma unroll
    for (int j = 0; j < 8; ++j) v[j] = tile[rc + j][cr];
    *(u16x8*)&out[(size_t)(c0 + cr) * R + r0 + rc] = v;
  }
}

// -------- extract V from qkv, transpose: vt[b][h][d=64][t=1024] bf16 --------
__global__ __launch_bounds__(256) void k_vtrans(const u16* __restrict__ qkv,
                                                u16* __restrict__ vt) {
  __shared__ u16 tile[64][65];
  int bid = blockIdx.x;
  int b = bid >> 8, h = (bid >> 4) & 15, tt = bid & 15;
  int tid = threadIdx.x;
#pragma unroll
  for (int rr = 0; rr < 2; ++rr) {
    int tl = rr * 32 + (tid >> 3);
    int d0 = (tid & 7) * 8;
    u16x8 v = *(const u16x8*)&qkv[(size_t)(b * 1024 + tt * 64 + tl) * 3072 + 2048 + h * 64 + d0];
#pragma unroll
    for (int j = 0; j < 8; ++j) tile[tl][d0 + j] = v[j];
  }
  __syncthreads();
#pragma unroll
  for (int rr = 0; rr < 2; ++rr) {
    int d = rr * 32 + (tid >> 3);
    int t0 = (tid & 7) * 8;
    u16x8 v;
#pragma unroll
    for (int j = 0; j < 8; ++j) v[j] = tile[t0 + j][d];
    *(u16x8*)&vt[((size_t)(b * 16 + h) * 64 + d) * 1024 + tt * 64 + t0] = v;
  }
}

// ---------------- lambda_full scalar ----------------
__global__ void k_lambda(const float* lq1, const float* lq2,
                         const float* lk1, const float* lk2, float* out) {
  int i = threadIdx.x;
  float a = 0.f, b = 0.f;
  if (i < 32) { a = lq1[i] * lk1[i]; b = lq2[i] * lk2[i]; }
#pragma unroll
  for (int s = 1; s < 64; s <<= 1) { a += __shfl_xor(a, s); b += __shfl_xor(b, s); }
  if (i == 0) out[0] = __expf(a) - __expf(b) + 0.2f;
}

// ------ bf16 GEMM: triple-buffer, SINGLE barrier/K-step, 2-deep prefetch ----
// Proof of barrier elision: at barrier_ki every wave has (a) counted-vmcnt
// verified its own stage(ki) landed, (b) finished compute(ki-1) in program
// order. stage(ki+2) (issued after barrier_ki) writes buf (ki+2)%3 ==
// (ki-1)%3, whose readers all finished by (b). 48 KB LDS -> 3 blocks/CU.
template <bool OUT_F32>
__global__ __launch_bounds__(256) void k_gemm(const u16* __restrict__ A,
                                              const u16* __restrict__ Bt,
                                              void* __restrict__ Cout,
                                              int M, int N, int K) {
  __shared__ __align__(16) u16 As[3][128 * 32];
  __shared__ __align__(16) u16 Bs[3][128 * 32];
  int tid = threadIdx.x;
  int nbn = N >> 7;
  int wg = ((int)blockIdx.x & 7) * ((int)gridDim.x >> 3) + ((int)blockIdx.x >> 3);
  int bm = wg / nbn, bn = wg % nbn;
  int m0 = bm << 7, n0 = bn << 7;
  int lane = tid & 63, w = tid >> 6, wm = w >> 1, wn = w & 1;
  int lr = lane & 15, lg = lane >> 4;
  const u16* pA0; const u16* pA1; const u16* pB0; const u16* pB1;
  {
    int i0 = tid, i1 = tid + 256;
    int r0 = i0 >> 2, s80 = (i0 & 3) ^ ((r0 >> 1) & 3);
    int r1 = i1 >> 2, s81 = (i1 & 3) ^ ((r1 >> 1) & 3);
    pA0 = &A[(size_t)(m0 + r0) * K + s80 * 8];
    pA1 = &A[(size_t)(m0 + r1) * K + s81 * 8];
    pB0 = &Bt[(size_t)(n0 + r0) * K + s80 * 8];
    pB1 = &Bt[(size_t)(n0 + r1) * K + s81 * 8];
  }
  f32x4 acc[4][4] = {};
  auto stage = [&](int kt, int buf) {
    gld16(pA0 + kt, &As[buf][tid * 8]);
    gld16(pA1 + kt, &As[buf][(tid + 256) * 8]);
    gld16(pB0 + kt, &Bs[buf][tid * 8]);
    gld16(pB1 + kt, &Bs[buf][(tid + 256) * 8]);
  };
  int NK = K >> 5;
  stage(0, 0);
  if (NK > 1) stage(32, 1);
  for (int ki = 0; ki < NK; ++ki) {
    if (ki + 1 < NK) {
      asm volatile("s_waitcnt vmcnt(4)" ::: "memory");
    } else {
      asm volatile("s_waitcnt vmcnt(0)" ::: "memory");
    }
    __builtin_amdgcn_s_barrier();
    __builtin_amdgcn_sched_barrier(0);
    if (ki + 2 < NK) stage((ki + 2) << 5, (ki + 2) % 3);
    int cur = ki % 3;
    bf16x8 af[4], bfr[4];
#pragma unroll
    for (int m = 0; m < 4; ++m) {
      int r = wm * 64 + m * 16 + lr;
      int c8 = lg ^ ((r >> 1) & 3);
      af[m] = *(const bf16x8*)&As[cur][r * 32 + c8 * 8];
    }
#pragma unroll
    for (int n = 0; n < 4; ++n) {
      int r = wn * 64 + n * 16 + lr;
      int c8 = lg ^ ((r >> 1) & 3);
      bfr[n] = *(const bf16x8*)&Bs[cur][r * 32 + c8 * 8];
    }
    __builtin_amdgcn_s_setprio(1);
#pragma unroll
    for (int m = 0; m < 4; ++m)
#pragma unroll
      for (int n = 0; n < 4; ++n)
        acc[m][n] = __builtin_amdgcn_mfma_f32_16x16x32_bf16(af[m], bfr[n], acc[m][n], 0, 0, 0);
    __builtin_amdgcn_s_setprio(0);
    __builtin_amdgcn_sched_barrier(0);
  }
#pragma unroll
  for (int m = 0; m < 4; ++m)
#pragma unroll
    for (int r = 0; r < 4; ++r) {
      int gr = m0 + wm * 64 + m * 16 + lg * 4 + r;
#pragma unroll
      for (int n = 0; n < 4; ++n) {
        int gc = n0 + wn * 64 + n * 16 + lr;
        if (OUT_F32) ((float*)Cout)[(size_t)gr * N + gc] = acc[m][n][r];
        else ((u16*)Cout)[(size_t)gr * N + gc] = f2bf(acc[m][n][r]);
      }
    }
}

// ---------------- differential flash attention (LPT dynamic balance) --------
// grid 1024 = one q-block per block; heavy blocks first (LPT). 50 KB LDS ->
// 3 blocks/CU; independent blocks overlap each other's serial chains.
// + T5: s_setprio(1) around MFMA clusters (m191: attn +4-7%).
__global__ __launch_bounds__(256) void k_diffattn(const u16* __restrict__ qkv,
                                                  const u16* __restrict__ vt,
                                                  const float* __restrict__ lam_p,
                                                  const float* __restrict__ gamma,
                                                  u16* __restrict__ attn_out) {
  __shared__ __align__(16) u16 Ks[2][2][64 * 32];  // 16 KB
  __shared__ __align__(16) u16 Vs[2][64 * 64];     // 16 KB
  __shared__ __align__(16) u16 Ps[4][2][16 * 72];  // 18 KB
  int bid = blockIdx.x;
  int qb = 15 - (bid >> 6);
  int b = (bid >> 4) & 3, h = bid & 15;
  int tid = threadIdx.x, lane = tid & 63, w = tid >> 6;
  int lr = lane & 15, lg = lane >> 4;
  int g1 = 2 * h, g2 = g1 + 1;
  float lam = *lam_p;
  const float cexp = 0.045084222f;  // log2(e)/32
  f32x4 zero = {0.f, 0.f, 0.f, 0.f};
  u16* P1 = &Ps[w][0][0];
  u16* P2 = &Ps[w][1][0];

  const u16* pK1; const u16* pK2;
  {
    int r = tid >> 2, c8 = tid & 3;
    int s8 = c8 ^ ((r >> 1) & 3);
    size_t krow = (size_t)(b * 1024 + r) * 3072 + 1024;
    pK1 = qkv + krow + g1 * 32 + s8 * 8;
    pK2 = qkv + krow + g2 * 32 + s8 * 8;
  }
  const u16* pV0; const u16* pV1;
  {
    const u16* vbase = vt + ((size_t)(b * 16 + h) * 64) * 1024;
    int d0 = tid >> 3, o0 = (tid & 7) ^ (d0 & 7);
    pV0 = vbase + (size_t)d0 * 1024 + o0 * 8;
    pV1 = vbase + (size_t)(d0 + 32) * 1024 + o0 * 8;
  }

  auto stage = [&](int s0, int buf) {
    gld16(pK1 + (size_t)s0 * 3072, &Ks[buf][0][tid * 8]);
    gld16(pK2 + (size_t)s0 * 3072, &Ks[buf][1][tid * 8]);
    gld16(pV0 + s0, &Vs[buf][tid * 8]);
    gld16(pV1 + s0, &Vs[buf][(tid + 256) * 8]);
  };

  int q0 = qb * 64;
  size_t qrow = (size_t)(b * 1024 + q0 + w * 16 + lr);
  bf16x8 qf1 = *(const bf16x8*)&qkv[qrow * 3072 + g1 * 32 + lg * 8];
  bf16x8 qf2 = *(const bf16x8*)&qkv[qrow * 3072 + g2 * 32 + lg * 8];
  f32x4 o1[4] = {}, o2[4] = {};
  float l1[4] = {}, l2[4] = {};
  int qg_base = q0 + w * 16 + lg * 4;

  auto tile = [&](int cur, int s0, auto mk) {
    f32x4 s1[4], s2[4];
    __builtin_amdgcn_s_setprio(1);
#pragma unroll
    for (int ni = 0; ni < 4; ++ni) {
      int rk = ni * 16 + lr;
      int c8 = lg ^ ((rk >> 1) & 3);
      bf16x8 kf1 = *(const bf16x8*)&Ks[cur][0][rk * 32 + c8 * 8];
      bf16x8 kf2 = *(const bf16x8*)&Ks[cur][1][rk * 32 + c8 * 8];
      s1[ni] = __builtin_amdgcn_mfma_f32_16x16x32_bf16(qf1, kf1, zero, 0, 0, 0);
      s2[ni] = __builtin_amdgcn_mfma_f32_16x16x32_bf16(qf2, kf2, zero, 0, 0, 0);
    }
    __builtin_amdgcn_s_setprio(0);
#pragma unroll
    for (int ni = 0; ni < 4; ++ni) {
      int sg = s0 + ni * 16 + lr;
#pragma unroll
      for (int r = 0; r < 4; ++r) {
        float v1 = fexp2(s1[ni][r] * cexp);
        float v2 = fexp2(s2[ni][r] * cexp);
        if constexpr (decltype(mk)::value) {
          if (sg > qg_base + r) { v1 = 0.f; v2 = 0.f; }
        }
        l1[r] += v1; l2[r] += v2;
        P1[(lg * 4 + r) * 72 + ni * 16 + lr] = f2bf_fast(v1);
        P2[(lg * 4 + r) * 72 + ni * 16 + lr] = f2bf_fast(v2);
      }
    }
    __builtin_amdgcn_s_setprio(1);
#pragma unroll
    for (int kk = 0; kk < 2; ++kk) {
      bf16x8 pa1 = *(const bf16x8*)&P1[lr * 72 + kk * 32 + lg * 8];
      bf16x8 pa2 = *(const bf16x8*)&P2[lr * 72 + kk * 32 + lg * 8];
#pragma unroll
      for (int ni = 0; ni < 4; ++ni) {
        int d = ni * 16 + lr;
        int c8 = (kk * 4 + lg) ^ (d & 7);
        bf16x8 vb = *(const bf16x8*)&Vs[cur][d * 64 + c8 * 8];
        o1[ni] = __builtin_amdgcn_mfma_f32_16x16x32_bf16(pa1, vb, o1[ni], 0, 0, 0);
        o2[ni] = __builtin_amdgcn_mfma_f32_16x16x32_bf16(pa2, vb, o2[ni], 0, 0, 0);
      }
    }
    __builtin_amdgcn_s_setprio(0);
  };

  stage(0, 0);
  for (int t = 0; t < qb; ++t) {
    int cur = t & 1;
    stage((t + 1) * 64, cur ^ 1);
    asm volatile("s_waitcnt vmcnt(4)" ::: "memory");
    __builtin_amdgcn_s_barrier();
    __builtin_amdgcn_sched_barrier(0);
    tile(cur, t * 64, BC<false>{});
    __builtin_amdgcn_sched_barrier(0);
    __builtin_amdgcn_s_barrier();
  }
  asm volatile("s_waitcnt vmcnt(0)" ::: "memory");
  __builtin_amdgcn_s_barrier();
  __builtin_amdgcn_sched_barrier(0);
  tile(qb & 1, q0, BC<true>{});

  // epilogue
#pragma unroll
  for (int r = 0; r < 4; ++r) {
    l1[r] += __shfl_xor(l1[r], 1); l1[r] += __shfl_xor(l1[r], 2);
    l1[r] += __shfl_xor(l1[r], 4); l1[r] += __shfl_xor(l1[r], 8);
    l2[r] += __shfl_xor(l2[r], 1); l2[r] += __shfl_xor(l2[r], 2);
    l2[r] += __shfl_xor(l2[r], 4); l2[r] += __shfl_xor(l2[r], 8);
  }
  float val[4][4];
#pragma unroll
  for (int ni = 0; ni < 4; ++ni)
#pragma unroll
    for (int r = 0; r < 4; ++r)
      val[ni][r] = o1[ni][r] * (1.f / l1[r]) - lam * (o2[ni][r] * (1.f / l2[r]));
#pragma unroll
  for (int r = 0; r < 4; ++r) {
    float ss = 0.f;
#pragma unroll
    for (int ni = 0; ni < 4; ++ni) ss += val[ni][r] * val[ni][r];
    ss += __shfl_xor(ss, 1); ss += __shfl_xor(ss, 2);
    ss += __shfl_xor(ss, 4); ss += __shfl_xor(ss, 8);
    float sc = rsqrtf(ss * (1.f / 64.f) + 1e-5f) * 0.8f;
#pragma unroll
    for (int ni = 0; ni < 4; ++ni) val[ni][r] *= sc;
  }
#pragma unroll
  for (int ni = 0; ni < 4; ++ni) {
    int d = ni * 16 + lr;
    float g = gamma[d];
#pragma unroll
    for (int r = 0; r < 4; ++r) {
      int trow = q0 + w * 16 + lg * 4 + r;
      attn_out[(size_t)(b * 1024 + trow) * 1024 + h * 64 + d] = f2bf(val[ni][r] * g);
    }
  }
}

// ---------------- launch ----------------
extern "C" void kernel_launch(void* const* d_in, const int* in_sizes, int n_in,
                              void* d_out, int out_size, void* d_ws, size_t ws_size,
                              hipStream_t stream) {
  const float* x   = (const float*)d_in[0];
  const float* wa  = (const float*)d_in[1];
  const float* wp  = (const float*)d_in[2];
  const float* lq1 = (const float*)d_in[3];
  const float* lq2 = (const float*)d_in[4];
  const float* lk1 = (const float*)d_in[5];
  const float* lk2 = (const float*)d_in[6];
  const float* gam = (const float*)d_in[7];
  float* out = (float*)d_out;

  char* ws = (char*)d_ws;
  u16* xb   = (u16*)(ws);                        // 8 MiB  [4096][1024]
  u16* wab  = (u16*)(ws + (8ull << 20));         // 6 MiB  [3072][1024] (w_attn^T)
  u16* wpb  = (u16*)(ws + (14ull << 20));        // 2 MiB  [1024][1024] (w_proj^T)
  u16* qkv  = (u16*)(ws + (16ull << 20));        // 24 MiB [4096][3072]
  u16* vt   = (u16*)(ws + (40ull << 20));        // 8 MiB  [4][16][64][1024]
  u16* aout = (u16*)(ws + (48ull << 20));        // 8 MiB  [4096][1024]
  float* lam = (float*)(ws + (56ull << 20));     // 4 B

  k_cast<<<4096, 256, 0, stream>>>(x, xb, 1024 * 1024);
  k_transpose_cast<<<dim3(16, 48), 256, 0, stream>>>(wa, wab, 1024, 3072);
  k_transpose_cast<<<dim3(16, 16), 256, 0, stream>>>(wp, wpb, 1024, 1024);
  k_lambda<<<1, 64, 0, stream>>>(lq1, lq2, lk1, lk2, lam);
  k_gemm<false><<<32 * 24, 256, 0, stream>>>(xb, wab, qkv, 4096, 3072, 1024);
  k_vtrans<<<1024, 256, 0, stream>>>(qkv, vt);
  k_diffattn<<<1024, 256, 0, stream>>>(qkv, vt, lam, gam, aout);
  k_gemm<true><<<32 * 8, 256, 0, stream>>>(aout, wpb, out, 4096, 1024, 1024);
}

// Round 11
// 180.399 us; speedup vs baseline: 1.1345x; 1.0326x over previous
//
#include <hip/hip_runtime.h>

typedef unsigned short u16;
typedef unsigned int u32;
typedef __bf16 bf16x8 __attribute__((ext_vector_type(8)));
typedef float f32x4 __attribute__((ext_vector_type(4)));
typedef u16 u16x8 __attribute__((ext_vector_type(8)));
typedef u16 u16x4 __attribute__((ext_vector_type(4)));

#define DEV static __device__ __forceinline__

template <bool B> struct BC { static constexpr bool value = B; };

DEV u16 f2bf(float f) {
  unsigned u = __builtin_bit_cast(unsigned, f);
  u += 0x7fffu + ((u >> 16) & 1u);
  return (u16)(u >> 16);
}
DEV u16 f2bf_fast(float f) {
  unsigned u = __builtin_bit_cast(unsigned, f);
  return (u16)((u + 0x8000u) >> 16);
}
DEV float fexp2(float x) {
  float r;
  asm("v_exp_f32 %0, %1" : "=v"(r) : "v"(x));
  return r;
}

DEV void gld16(const void* g, void* l) {
  __builtin_amdgcn_global_load_lds((__attribute__((address_space(1))) void*)(g),
                                   (__attribute__((address_space(3))) void*)(l),
                                   16, 0, 0);
}

// -------- fused prep: cast(x) | transpose(w_attn) | transpose(w_proj) | lambda
// grid 5121: [0,4096) cast; [4096,4864) w_attn tiles; [4864,5120) w_proj;
// 5120 lambda. Independent sections, one launch (saves 3 launch gaps).
__global__ __launch_bounds__(256) void k_prep(const float* __restrict__ x,
                                              const float* __restrict__ wa,
                                              const float* __restrict__ wp,
                                              const float* __restrict__ lq1,
                                              const float* __restrict__ lq2,
                                              const float* __restrict__ lk1,
                                              const float* __restrict__ lk2,
                                              u16* __restrict__ xb,
                                              u16* __restrict__ wab,
                                              u16* __restrict__ wpb,
                                              float* __restrict__ lam) {
  __shared__ u16 tile[64][65];
  int bid = blockIdx.x, tid = threadIdx.x;
  if (bid < 4096) {  // cast
    int i = bid * 256 + tid;
    float4 v = ((const float4*)x)[i];
    u16x4 r = { f2bf(v.x), f2bf(v.y), f2bf(v.z), f2bf(v.w) };
    ((u16x4*)xb)[i] = r;
    return;
  }
  if (bid == 5120) {  // lambda
    int i = tid;
    float a = 0.f, b = 0.f;
    if (i < 32) { a = lq1[i] * lk1[i]; b = lq2[i] * lk2[i]; }
#pragma unroll
    for (int s = 1; s < 64; s <<= 1) { a += __shfl_xor(a, s); b += __shfl_xor(b, s); }
    if (i == 0) lam[0] = __expf(a) - __expf(b) + 0.2f;
    return;
  }
  // transpose_cast sections
  const float* in; u16* out; int R, Cc, local;
  if (bid < 4864) { in = wa; out = wab; R = 1024; Cc = 3072; local = bid - 4096; }
  else            { in = wp; out = wpb; R = 1024; Cc = 1024; local = bid - 4864; }
  int r0 = (local & 15) * 64, c0 = (local >> 4) * 64;
#pragma unroll
  for (int rr = 0; rr < 4; ++rr) {
    int r = rr * 16 + (tid >> 4);
    int c = (tid & 15) * 4;
    float4 v = *(const float4*)&in[(size_t)(r0 + r) * Cc + c0 + c];
    tile[r][c + 0] = f2bf(v.x); tile[r][c + 1] = f2bf(v.y);
    tile[r][c + 2] = f2bf(v.z); tile[r][c + 3] = f2bf(v.w);
  }
  __syncthreads();
#pragma unroll
  for (int rr = 0; rr < 2; ++rr) {
    int cr = rr * 32 + (tid >> 3);
    int rc = (tid & 7) * 8;
    u16x8 v;
#pragma unroll
    for (int j = 0; j < 8; ++j) v[j] = tile[rc + j][cr];
    *(u16x8*)&out[(size_t)(c0 + cr) * R + r0 + rc] = v;
  }
}

// -------- extract V from qkv, transpose: vt[b][h][d=64][t=1024] bf16 --------
__global__ __launch_bounds__(256) void k_vtrans(const u16* __restrict__ qkv,
                                                u16* __restrict__ vt) {
  __shared__ u16 tile[64][65];
  int bid = blockIdx.x;
  int b = bid >> 8, h = (bid >> 4) & 15, tt = bid & 15;
  int tid = threadIdx.x;
#pragma unroll
  for (int rr = 0; rr < 2; ++rr) {
    int tl = rr * 32 + (tid >> 3);
    int d0 = (tid & 7) * 8;
    u16x8 v = *(const u16x8*)&qkv[(size_t)(b * 1024 + tt * 64 + tl) * 3072 + 2048 + h * 64 + d0];
#pragma unroll
    for (int j = 0; j < 8; ++j) tile[tl][d0 + j] = v[j];
  }
  __syncthreads();
#pragma unroll
  for (int rr = 0; rr < 2; ++rr) {
    int d = rr * 32 + (tid >> 3);
    int t0 = (tid & 7) * 8;
    u16x8 v;
#pragma unroll
    for (int j = 0; j < 8; ++j) v[j] = tile[t0 + j][d];
    *(u16x8*)&vt[((size_t)(b * 16 + h) * 64 + d) * 1024 + tt * 64 + t0] = v;
  }
}

// ------ bf16 GEMM: triple-buffer, single barrier/K-step, 2-deep prefetch ----
// 2D XCD chunking: 4x2 super-grid of XCDs; each XCD owns an rm x rn tile
// rectangle (rm=nbm/4, rn=nbn/2) -> concurrent working set A 2MB + B 3MB
// ~= L2-resident (was 7MB with 1D swizzle). Requires nbm%4==0 && nbn%2==0.
template <bool OUT_F32>
__global__ __launch_bounds__(256) void k_gemm(const u16* __restrict__ A,
                                              const u16* __restrict__ Bt,
                                              void* __restrict__ Cout,
                                              int M, int N, int K) {
  __shared__ __align__(16) u16 As[3][128 * 32];
  __shared__ __align__(16) u16 Bs[3][128 * 32];
  int tid = threadIdx.x;
  int nbm = M >> 7, nbn = N >> 7;
  int xcd = (int)blockIdx.x & 7;
  int local = (int)blockIdx.x >> 3;
  int rm = nbm >> 2, rn = nbn >> 1;
  int bm = (xcd >> 1) * rm + local % rm;
  int bn = (xcd & 1) * rn + local / rm;
  int m0 = bm << 7, n0 = bn << 7;
  int lane = tid & 63, w = tid >> 6, wm = w >> 1, wn = w & 1;
  int lr = lane & 15, lg = lane >> 4;
  const u16* pA0; const u16* pA1; const u16* pB0; const u16* pB1;
  {
    int i0 = tid, i1 = tid + 256;
    int r0 = i0 >> 2, s80 = (i0 & 3) ^ ((r0 >> 1) & 3);
    int r1 = i1 >> 2, s81 = (i1 & 3) ^ ((r1 >> 1) & 3);
    pA0 = &A[(size_t)(m0 + r0) * K + s80 * 8];
    pA1 = &A[(size_t)(m0 + r1) * K + s81 * 8];
    pB0 = &Bt[(size_t)(n0 + r0) * K + s80 * 8];
    pB1 = &Bt[(size_t)(n0 + r1) * K + s81 * 8];
  }
  f32x4 acc[4][4] = {};
  auto stage = [&](int kt, int buf) {
    gld16(pA0 + kt, &As[buf][tid * 8]);
    gld16(pA1 + kt, &As[buf][(tid + 256) * 8]);
    gld16(pB0 + kt, &Bs[buf][tid * 8]);
    gld16(pB1 + kt, &Bs[buf][(tid + 256) * 8]);
  };
  int NK = K >> 5;
  stage(0, 0);
  if (NK > 1) stage(32, 1);
  for (int ki = 0; ki < NK; ++ki) {
    if (ki + 1 < NK) {
      asm volatile("s_waitcnt vmcnt(4)" ::: "memory");
    } else {
      asm volatile("s_waitcnt vmcnt(0)" ::: "memory");
    }
    __builtin_amdgcn_s_barrier();
    __builtin_amdgcn_sched_barrier(0);
    if (ki + 2 < NK) stage((ki + 2) << 5, (ki + 2) % 3);
    int cur = ki % 3;
    bf16x8 af[4], bfr[4];
#pragma unroll
    for (int m = 0; m < 4; ++m) {
      int r = wm * 64 + m * 16 + lr;
      int c8 = lg ^ ((r >> 1) & 3);
      af[m] = *(const bf16x8*)&As[cur][r * 32 + c8 * 8];
    }
#pragma unroll
    for (int n = 0; n < 4; ++n) {
      int r = wn * 64 + n * 16 + lr;
      int c8 = lg ^ ((r >> 1) & 3);
      bfr[n] = *(const bf16x8*)&Bs[cur][r * 32 + c8 * 8];
    }
    __builtin_amdgcn_s_setprio(1);
#pragma unroll
    for (int m = 0; m < 4; ++m)
#pragma unroll
      for (int n = 0; n < 4; ++n)
        acc[m][n] = __builtin_amdgcn_mfma_f32_16x16x32_bf16(af[m], bfr[n], acc[m][n], 0, 0, 0);
    __builtin_amdgcn_s_setprio(0);
    __builtin_amdgcn_sched_barrier(0);
  }
#pragma unroll
  for (int m = 0; m < 4; ++m)
#pragma unroll
    for (int r = 0; r < 4; ++r) {
      int gr = m0 + wm * 64 + m * 16 + lg * 4 + r;
#pragma unroll
      for (int n = 0; n < 4; ++n) {
        int gc = n0 + wn * 64 + n * 16 + lr;
        if (OUT_F32) ((float*)Cout)[(size_t)gr * N + gc] = acc[m][n][r];
        else ((u16*)Cout)[(size_t)gr * N + gc] = f2bf(acc[m][n][r]);
      }
    }
}

// ---------------- differential flash attention (unchanged from R9) ----------
__global__ __launch_bounds__(256) void k_diffattn(const u16* __restrict__ qkv,
                                                  const u16* __restrict__ vt,
                                                  const float* __restrict__ lam_p,
                                                  const float* __restrict__ gamma,
                                                  u16* __restrict__ attn_out) {
  __shared__ __align__(16) u16 Ks[2][2][64 * 32];  // 16 KB
  __shared__ __align__(16) u16 Vs[2][64 * 64];     // 16 KB
  __shared__ __align__(16) u16 Ps[4][2][16 * 72];  // 18 KB
  int bid = blockIdx.x;
  int qb = 15 - (bid >> 6);
  int b = (bid >> 4) & 3, h = bid & 15;
  int tid = threadIdx.x, lane = tid & 63, w = tid >> 6;
  int lr = lane & 15, lg = lane >> 4;
  int g1 = 2 * h, g2 = g1 + 1;
  float lam = *lam_p;
  const float cexp = 0.045084222f;  // log2(e)/32
  f32x4 zero = {0.f, 0.f, 0.f, 0.f};
  u16* P1 = &Ps[w][0][0];
  u16* P2 = &Ps[w][1][0];

  const u16* pK1; const u16* pK2;
  {
    int r = tid >> 2, c8 = tid & 3;
    int s8 = c8 ^ ((r >> 1) & 3);
    size_t krow = (size_t)(b * 1024 + r) * 3072 + 1024;
    pK1 = qkv + krow + g1 * 32 + s8 * 8;
    pK2 = qkv + krow + g2 * 32 + s8 * 8;
  }
  const u16* pV0; const u16* pV1;
  {
    const u16* vbase = vt + ((size_t)(b * 16 + h) * 64) * 1024;
    int d0 = tid >> 3, o0 = (tid & 7) ^ (d0 & 7);
    pV0 = vbase + (size_t)d0 * 1024 + o0 * 8;
    pV1 = vbase + (size_t)(d0 + 32) * 1024 + o0 * 8;
  }

  auto stage = [&](int s0, int buf) {
    gld16(pK1 + (size_t)s0 * 3072, &Ks[buf][0][tid * 8]);
    gld16(pK2 + (size_t)s0 * 3072, &Ks[buf][1][tid * 8]);
    gld16(pV0 + s0, &Vs[buf][tid * 8]);
    gld16(pV1 + s0, &Vs[buf][(tid + 256) * 8]);
  };

  int q0 = qb * 64;
  size_t qrow = (size_t)(b * 1024 + q0 + w * 16 + lr);
  bf16x8 qf1 = *(const bf16x8*)&qkv[qrow * 3072 + g1 * 32 + lg * 8];
  bf16x8 qf2 = *(const bf16x8*)&qkv[qrow * 3072 + g2 * 32 + lg * 8];
  f32x4 o1[4] = {}, o2[4] = {};
  float l1[4] = {}, l2[4] = {};
  int qg_base = q0 + w * 16 + lg * 4;

  auto tile = [&](int cur, int s0, auto mk) {
    f32x4 s1[4], s2[4];
    __builtin_amdgcn_s_setprio(1);
#pragma unroll
    for (int ni = 0; ni < 4; ++ni) {
      int rk = ni * 16 + lr;
      int c8 = lg ^ ((rk >> 1) & 3);
      bf16x8 kf1 = *(const bf16x8*)&Ks[cur][0][rk * 32 + c8 * 8];
      bf16x8 kf2 = *(const bf16x8*)&Ks[cur][1][rk * 32 + c8 * 8];
      s1[ni] = __builtin_amdgcn_mfma_f32_16x16x32_bf16(qf1, kf1, zero, 0, 0, 0);
      s2[ni] = __builtin_amdgcn_mfma_f32_16x16x32_bf16(qf2, kf2, zero, 0, 0, 0);
    }
    __builtin_amdgcn_s_setprio(0);
#pragma unroll
    for (int ni = 0; ni < 4; ++ni) {
      int sg = s0 + ni * 16 + lr;
#pragma unroll
      for (int r = 0; r < 4; ++r) {
        float v1 = fexp2(s1[ni][r] * cexp);
        float v2 = fexp2(s2[ni][r] * cexp);
        if constexpr (decltype(mk)::value) {
          if (sg > qg_base + r) { v1 = 0.f; v2 = 0.f; }
        }
        l1[r] += v1; l2[r] += v2;
        P1[(lg * 4 + r) * 72 + ni * 16 + lr] = f2bf_fast(v1);
        P2[(lg * 4 + r) * 72 + ni * 16 + lr] = f2bf_fast(v2);
      }
    }
    __builtin_amdgcn_s_setprio(1);
#pragma unroll
    for (int kk = 0; kk < 2; ++kk) {
      bf16x8 pa1 = *(const bf16x8*)&P1[lr * 72 + kk * 32 + lg * 8];
      bf16x8 pa2 = *(const bf16x8*)&P2[lr * 72 + kk * 32 + lg * 8];
#pragma unroll
      for (int ni = 0; ni < 4; ++ni) {
        int d = ni * 16 + lr;
        int c8 = (kk * 4 + lg) ^ (d & 7);
        bf16x8 vb = *(const bf16x8*)&Vs[cur][d * 64 + c8 * 8];
        o1[ni] = __builtin_amdgcn_mfma_f32_16x16x32_bf16(pa1, vb, o1[ni], 0, 0, 0);
        o2[ni] = __builtin_amdgcn_mfma_f32_16x16x32_bf16(pa2, vb, o2[ni], 0, 0, 0);
      }
    }
    __builtin_amdgcn_s_setprio(0);
  };

  stage(0, 0);
  for (int t = 0; t < qb; ++t) {
    int cur = t & 1;
    stage((t + 1) * 64, cur ^ 1);
    asm volatile("s_waitcnt vmcnt(4)" ::: "memory");
    __builtin_amdgcn_s_barrier();
    __builtin_amdgcn_sched_barrier(0);
    tile(cur, t * 64, BC<false>{});
    __builtin_amdgcn_sched_barrier(0);
    __builtin_amdgcn_s_barrier();
  }
  asm volatile("s_waitcnt vmcnt(0)" ::: "memory");
  __builtin_amdgcn_s_barrier();
  __builtin_amdgcn_sched_barrier(0);
  tile(qb & 1, q0, BC<true>{});

  // epilogue
#pragma unroll
  for (int r = 0; r < 4; ++r) {
    l1[r] += __shfl_xor(l1[r], 1); l1[r] += __shfl_xor(l1[r], 2);
    l1[r] += __shfl_xor(l1[r], 4); l1[r] += __shfl_xor(l1[r], 8);
    l2[r] += __shfl_xor(l2[r], 1); l2[r] += __shfl_xor(l2[r], 2);
    l2[r] += __shfl_xor(l2[r], 4); l2[r] += __shfl_xor(l2[r], 8);
  }
  float val[4][4];
#pragma unroll
  for (int ni = 0; ni < 4; ++ni)
#pragma unroll
    for (int r = 0; r < 4; ++r)
      val[ni][r] = o1[ni][r] * (1.f / l1[r]) - lam * (o2[ni][r] * (1.f / l2[r]));
#pragma unroll
  for (int r = 0; r < 4; ++r) {
    float ss = 0.f;
#pragma unroll
    for (int ni = 0; ni < 4; ++ni) ss += val[ni][r] * val[ni][r];
    ss += __shfl_xor(ss, 1); ss += __shfl_xor(ss, 2);
    ss += __shfl_xor(ss, 4); ss += __shfl_xor(ss, 8);
    float sc = rsqrtf(ss * (1.f / 64.f) + 1e-5f) * 0.8f;
#pragma unroll
    for (int ni = 0; ni < 4; ++ni) val[ni][r] *= sc;
  }
#pragma unroll
  for (int ni = 0; ni < 4; ++ni) {
    int d = ni * 16 + lr;
    float g = gamma[d];
#pragma unroll
    for (int r = 0; r < 4; ++r) {
      int trow = q0 + w * 16 + lg * 4 + r;
      attn_out[(size_t)(b * 1024 + trow) * 1024 + h * 64 + d] = f2bf(val[ni][r] * g);
    }
  }
}

// ---------------- launch ----------------
extern "C" void kernel_launch(void* const* d_in, const int* in_sizes, int n_in,
                              void* d_out, int out_size, void* d_ws, size_t ws_size,
                              hipStream_t stream) {
  const float* x   = (const float*)d_in[0];
  const float* wa  = (const float*)d_in[1];
  const float* wp  = (const float*)d_in[2];
  const float* lq1 = (const float*)d_in[3];
  const float* lq2 = (const float*)d_in[4];
  const float* lk1 = (const float*)d_in[5];
  const float* lk2 = (const float*)d_in[6];
  const float* gam = (const float*)d_in[7];
  float* out = (float*)d_out;

  char* ws = (char*)d_ws;
  u16* xb   = (u16*)(ws);                        // 8 MiB  [4096][1024]
  u16* wab  = (u16*)(ws + (8ull << 20));         // 6 MiB  [3072][1024] (w_attn^T)
  u16* wpb  = (u16*)(ws + (14ull << 20));        // 2 MiB  [1024][1024] (w_proj^T)
  u16* qkv  = (u16*)(ws + (16ull << 20));        // 24 MiB [4096][3072]
  u16* vt   = (u16*)(ws + (40ull << 20));        // 8 MiB  [4][16][64][1024]
  u16* aout = (u16*)(ws + (48ull << 20));        // 8 MiB  [4096][1024]
  float* lam = (float*)(ws + (56ull << 20));     // 4 B

  k_prep<<<5121, 256, 0, stream>>>(x, wa, wp, lq1, lq2, lk1, lk2, xb, wab, wpb, lam);
  k_gemm<false><<<32 * 24, 256, 0, stream>>>(xb, wab, qkv, 4096, 3072, 1024);
  k_vtrans<<<1024, 256, 0, stream>>>(qkv, vt);
  k_diffattn<<<1024, 256, 0, stream>>>(qkv, vt, lam, gam, aout);
  k_gemm<true><<<32 * 8, 256, 0, stream>>>(aout, wpb, out, 4096, 1024, 1024);
}